// Round 1
// 948.564 us; speedup vs baseline: 1.0501x; 1.0501x over previous
//
#include <hip/hip_runtime.h>
#include <hip/hip_bf16.h>
#include <math.h>

// Decoder: B=4096 T=5 V=8192 E=32 H=512 O=1024
// Pipeline: [prep: bf16 weights + x0 + h0=0] -> [embed GEMM+LN -> xs[1..4]] ->
//           5x [GRU step: (h@Whh^T + x@Wih^T) gates, MFMA bf16] -> [row LN] ->
//           [FC GEMM + sigmoid -> fp32 out]
// NOTE: reference computes emb for t=0..4 but only t=0..3 feed the GRU -> we
// skip message[:,4,:] entirely (537MB instead of 671MB read).
// R1: k_embed rewritten as barrier-free streaming GEMM: split-K=4 across the
//     4 waves of a block (1024 blocks, 16 waves/CU), A loaded global->reg with
//     in-reg fp32->bf16 convert (no LDS staging, no syncthreads in K-loop),
//     B fragments direct from L2-resident embW_bf. LDS only for the 4-way
//     split-K reduce + fused LN epilogue.
// ws usage: ~17.2 MB (see carve-out in kernel_launch).

#define LN_EPS 1e-5f

typedef __attribute__((ext_vector_type(8))) short bf8;   // 8 bf16 (4 VGPRs) — MFMA A/B frag
typedef __attribute__((ext_vector_type(4))) float fx4;   // 4 fp32 — MFMA C/D frag

__device__ __forceinline__ float bf2f(short s) {
    union { unsigned u; float f; } v;
    v.u = ((unsigned)(unsigned short)s) << 16;
    return v.f;
}
__device__ __forceinline__ short f2bf(float f) {
    union { __hip_bfloat16 h; unsigned short u; } v;
    v.h = __float2bfloat16(f);   // RNE
    return (short)v.u;
}
__device__ __forceinline__ float sigmoidf(float x) { return 1.0f / (1.0f + expf(-x)); }

// ---------------------------------------------------------------- k_prep
// Convert weights fp32->bf16, zero h0, compute x0 = LN(init_emb)*g+b (bf16).
__global__ __launch_bounds__(256) void k_prep(
    const float* __restrict__ Whh, const float* __restrict__ Wih,
    const float* __restrict__ fcW, const float* __restrict__ embW,
    const float* __restrict__ init_emb, const float* __restrict__ eln_g,
    const float* __restrict__ eln_b,
    short* __restrict__ Whh_bf, short* __restrict__ Wih_bf,
    short* __restrict__ fcW_bf, short* __restrict__ embW_bf,
    short* __restrict__ x0v, short* __restrict__ h0)
{
    int gid = blockIdx.x * blockDim.x + threadIdx.x;
    int stride = gridDim.x * blockDim.x;
    for (int i = gid; i < 1536 * 512; i += stride) Whh_bf[i] = f2bf(Whh[i]);
    for (int i = gid; i < 1536 * 32;  i += stride) Wih_bf[i] = f2bf(Wih[i]);
    for (int i = gid; i < 1024 * 512; i += stride) fcW_bf[i] = f2bf(fcW[i]);
    for (int i = gid; i < 32 * 8192;  i += stride) embW_bf[i] = f2bf(embW[i]);
    // zero initial hidden state (bf16 zeros == 0x0000)
    int* h0i = (int*)h0;
    for (int i = gid; i < 4096 * 512 / 2; i += stride) h0i[i] = 0;
    // x0 = LN(init_emb) — one 32-lane group
    if (blockIdx.x == 0 && threadIdx.x < 32) {
        float v = init_emb[threadIdx.x];
        float s = v, q = v * v;
        #pragma unroll
        for (int m = 1; m < 32; m <<= 1) { s += __shfl_xor(s, m); q += __shfl_xor(q, m); }
        float mean = s * (1.0f / 32.0f);
        float var  = q * (1.0f / 32.0f) - mean * mean;
        float rstd = rsqrtf(var + LN_EPS);
        x0v[threadIdx.x] = f2bf((v - mean) * rstd * eln_g[threadIdx.x] + eln_b[threadIdx.x]);
    }
}

// ---------------------------------------------------------------- k_embed
// C[16384,32] = message_rows(b,t<=3) @ embW^T, then LN over E=32 -> xs[t+1][b][:]
// Row index rg = b*4 + t. Block: 16 rows. 4 waves = 4 K-quarters (split-K),
// barrier-free main loop: A global->reg (fp32->bf16 in-reg), B direct bf8 loads.
// Epilogue: LDS reduce of 4 partials + fused bias/LN.
__global__ __launch_bounds__(256) void k_embed(
    const float* __restrict__ msg, const short* __restrict__ embW_bf,
    const float* __restrict__ emb_b, const float* __restrict__ eln_g,
    const float* __restrict__ eln_b, short* __restrict__ xs)
{
    __shared__ float part[4][16][33];   // +1 pad: conflict-free partial writes

    const int tid  = threadIdx.x;
    const int w    = tid >> 6;          // wave id = K-quarter
    const int lane = tid & 63;
    const int m    = lane & 15;
    const int quad = lane >> 4;

    // A rows: rg = blockIdx.x*16 + m  (rg = b*4 + t, t<=3 only by construction)
    const int rg = blockIdx.x * 16 + m;
    const int b  = rg >> 2, t = rg & 3;
    const float* __restrict__ row = msg + (size_t)(b * 5 + t) * 8192;

    const short* __restrict__ bw0 = embW_bf + (size_t)m * 8192;          // cols 0..15
    const short* __restrict__ bw1 = embW_bf + (size_t)(16 + m) * 8192;   // cols 16..31

    fx4 acc0, acc1;
    #pragma unroll
    for (int j = 0; j < 4; ++j) { acc0[j] = 0.0f; acc1[j] = 0.0f; }

    const int kbeg = w * 2048;
    const int kend = kbeg + 2048;
    #pragma unroll 4
    for (int k0 = kbeg; k0 < kend; k0 += 32) {
        const int kq = k0 + quad * 8;
        float4 a0 = *(const float4*)(row + kq);
        float4 a1 = *(const float4*)(row + kq + 4);
        bf8 a;
        a[0] = f2bf(a0.x); a[1] = f2bf(a0.y); a[2] = f2bf(a0.z); a[3] = f2bf(a0.w);
        a[4] = f2bf(a1.x); a[5] = f2bf(a1.y); a[6] = f2bf(a1.z); a[7] = f2bf(a1.w);
        bf8 b0 = *(const bf8*)(bw0 + kq);
        bf8 b1 = *(const bf8*)(bw1 + kq);
        acc0 = __builtin_amdgcn_mfma_f32_16x16x32_bf16(a, b0, acc0, 0, 0, 0);
        acc1 = __builtin_amdgcn_mfma_f32_16x16x32_bf16(a, b1, acc1, 0, 0, 0);
    }

    // park split-K partials (C layout: row = quad*4+r, col = nt*16+m)
    #pragma unroll
    for (int r = 0; r < 4; ++r) {
        part[w][quad * 4 + r][m]      = acc0[r];
        part[w][quad * 4 + r][16 + m] = acc1[r];
    }
    __syncthreads();

    // reduce 4 partials + bias, then per-row LN (rows are 32-lane groups)
    {
        const int rr = tid >> 5;        // 0..7
        const int c  = tid & 31;
        #pragma unroll
        for (int half = 0; half < 2; ++half) {
            const int r = rr + half * 8;
            float v = part[0][r][c] + part[1][r][c] + part[2][r][c] + part[3][r][c]
                    + emb_b[c];
            float s = v, q = v * v;
            #pragma unroll
            for (int msk = 1; msk < 32; msk <<= 1) {
                s += __shfl_xor(s, msk); q += __shfl_xor(q, msk);
            }
            float mean = s * (1.0f / 32.0f);
            float var  = q * (1.0f / 32.0f) - mean * mean;
            float rstd = rsqrtf(var + LN_EPS);
            const int rg2 = blockIdx.x * 16 + r;
            const int b2 = rg2 >> 2, t2 = rg2 & 3;
            xs[(size_t)(t2 + 1) * 131072 + (size_t)b2 * 32 + c] =
                f2bf((v - mean) * rstd * eln_g[c] + eln_b[c]);
        }
    }
}

// ---------------------------------------------------------------- k_gru_step
// Block: 64 batch rows x 32 h-cols (j0). Computes six GEMM strips:
//   acc_h[s*2+nt] from h@Whh rows {s*512+j}, acc_i from x@Wih rows {s*512+j}
// then gates: r=sig(ir+hr), z=sig(iz+hz), n=tanh(inn+r*hn), h'=(1-z)n+z*h.
__global__ __launch_bounds__(256) void k_gru_step(
    const short* __restrict__ x, int x_stride,
    const short* __restrict__ h_in, short* __restrict__ h_out,
    const short* __restrict__ Whh_bf, const short* __restrict__ Wih_bf,
    const float* __restrict__ bih, const float* __restrict__ bhh)
{
    __shared__ short Hs[64][72];
    __shared__ short Ws[96][72];
    __shared__ short Xs[64][40];
    __shared__ short WIs[96][40];

    const int tid  = threadIdx.x;
    const int wid  = tid >> 6;
    const int lane = tid & 63;
    const int m    = lane & 15;
    const int quad = lane >> 4;
    const int row0 = blockIdx.x * 64;
    const int j0   = blockIdx.y * 32;

    fx4 acc_h[6], acc_i[6];
    #pragma unroll
    for (int i = 0; i < 6; ++i)
        #pragma unroll
        for (int j = 0; j < 4; ++j) { acc_h[i][j] = 0.0f; acc_i[i][j] = 0.0f; }

    // stage x tile (64x32) and Wih gathered rows (96x32) once
    {
        int c = tid;                       // 256 chunks
        int r = c >> 2, kp = (c & 3) * 8;
        const short* src = x + (size_t)(row0 + r) * x_stride + kp;
        *(bf8*)&Xs[r][kp] = *(const bf8*)src;
    }
    #pragma unroll
    for (int i = 0; i < 2; ++i) {
        int c = tid + i * 256;             // 384 chunks
        if (c < 384) {
            int n = c >> 2, kp = (c & 3) * 8;
            int s = n >> 5, jj = n & 31;
            int g = s * 512 + j0 + jj;
            *(bf8*)&WIs[n][kp] = *(const bf8*)(Wih_bf + (size_t)g * 32 + kp);
        }
    }

    for (int k0 = 0; k0 < 512; k0 += 64) {
        #pragma unroll
        for (int i = 0; i < 2; ++i) {
            int c = tid + i * 256;         // 512 chunks (Hs)
            int r = c >> 3, kp = (c & 7) * 8;
            *(bf8*)&Hs[r][kp] = *(const bf8*)(h_in + (size_t)(row0 + r) * 512 + k0 + kp);
        }
        #pragma unroll
        for (int i = 0; i < 3; ++i) {
            int c = tid + i * 256;         // 768 chunks (Ws)
            int n = c >> 3, kp = (c & 7) * 8;
            int s = n >> 5, jj = n & 31;
            int g = s * 512 + j0 + jj;
            *(bf8*)&Ws[n][kp] = *(const bf8*)(Whh_bf + (size_t)g * 512 + k0 + kp);
        }
        __syncthreads();
        #pragma unroll
        for (int kk = 0; kk < 64; kk += 32) {
            bf8 a = *(const bf8*)&Hs[wid * 16 + m][kk + quad * 8];
            #pragma unroll
            for (int nt = 0; nt < 6; ++nt) {
                bf8 b = *(const bf8*)&Ws[(nt >> 1) * 32 + (nt & 1) * 16 + m][kk + quad * 8];
                acc_h[nt] = __builtin_amdgcn_mfma_f32_16x16x32_bf16(a, b, acc_h[nt], 0, 0, 0);
            }
        }
        __syncthreads();
    }
    // gi contribution: single K=32 chunk (Xs/WIs staged pre-loop; syncs above cover)
    {
        bf8 a = *(const bf8*)&Xs[wid * 16 + m][quad * 8];
        #pragma unroll
        for (int nt = 0; nt < 6; ++nt) {
            bf8 b = *(const bf8*)&WIs[(nt >> 1) * 32 + (nt & 1) * 16 + m][quad * 8];
            acc_i[nt] = __builtin_amdgcn_mfma_f32_16x16x32_bf16(a, b, acc_i[nt], 0, 0, 0);
        }
    }
    // gates
    #pragma unroll
    for (int nt = 0; nt < 2; ++nt) {
        #pragma unroll
        for (int r = 0; r < 4; ++r) {
            int j  = j0 + nt * 16 + m;
            int rg = row0 + wid * 16 + quad * 4 + r;
            float rpre = acc_i[0 + nt][r] + bih[j]        + acc_h[0 + nt][r] + bhh[j];
            float zpre = acc_i[2 + nt][r] + bih[512 + j]  + acc_h[2 + nt][r] + bhh[512 + j];
            float inn  = acc_i[4 + nt][r] + bih[1024 + j];
            float hn   = acc_h[4 + nt][r] + bhh[1024 + j];
            float rr = sigmoidf(rpre);
            float zz = sigmoidf(zpre);
            float nn = tanhf(inn + rr * hn);
            float ho = bf2f(h_in[(size_t)rg * 512 + j]);
            h_out[(size_t)rg * 512 + j] = f2bf((1.0f - zz) * nn + zz * ho);
        }
    }
}

// ---------------------------------------------------------------- k_hln
// Row-wise LN of final h (H=512): one wave per row.
__global__ __launch_bounds__(256) void k_hln(
    const short* __restrict__ h, const float* __restrict__ g,
    const float* __restrict__ b, short* __restrict__ hln)
{
    int wid = threadIdx.x >> 6, lane = threadIdx.x & 63;
    int row = blockIdx.x * 4 + wid;
    bf8 v = *(const bf8*)(h + (size_t)row * 512 + lane * 8);
    float f[8];
    float sum = 0.f, sq = 0.f;
    #pragma unroll
    for (int i = 0; i < 8; ++i) { f[i] = bf2f(v[i]); sum += f[i]; sq += f[i] * f[i]; }
    #pragma unroll
    for (int msk = 1; msk < 64; msk <<= 1) { sum += __shfl_xor(sum, msk); sq += __shfl_xor(sq, msk); }
    float mean = sum * (1.0f / 512.0f);
    float var  = sq * (1.0f / 512.0f) - mean * mean;
    float rstd = rsqrtf(var + LN_EPS);
    short o[8];
    #pragma unroll
    for (int i = 0; i < 8; ++i) {
        int col = lane * 8 + i;
        o[i] = f2bf((f[i] - mean) * rstd * g[col] + b[col]);
    }
    *(bf8*)(hln + (size_t)row * 512 + lane * 8) = *(bf8*)o;
}

// ---------------------------------------------------------------- k_fc
// out[4096,1024] = sigmoid(hln @ fcW^T + fc_b), fp32 out.
__global__ __launch_bounds__(256) void k_fc(
    const short* __restrict__ hln, const short* __restrict__ fcW_bf,
    const float* __restrict__ fc_b, float* __restrict__ out)
{
    __shared__ short As[64][72];
    __shared__ short Bs[64][72];

    const int tid  = threadIdx.x;
    const int wid  = tid >> 6;
    const int lane = tid & 63;
    const int m    = lane & 15;
    const int quad = lane >> 4;
    const int row0 = blockIdx.x * 64;
    const int col0 = blockIdx.y * 64;

    fx4 acc[4];
    #pragma unroll
    for (int i = 0; i < 4; ++i)
        #pragma unroll
        for (int j = 0; j < 4; ++j) acc[i][j] = 0.0f;

    for (int k0 = 0; k0 < 512; k0 += 64) {
        #pragma unroll
        for (int i = 0; i < 2; ++i) {
            int c = tid + i * 256;
            int r = c >> 3, kp = (c & 7) * 8;
            *(bf8*)&As[r][kp] = *(const bf8*)(hln + (size_t)(row0 + r) * 512 + k0 + kp);
        }
        #pragma unroll
        for (int i = 0; i < 2; ++i) {
            int c = tid + i * 256;
            int n = c >> 3, kp = (c & 7) * 8;
            *(bf8*)&Bs[n][kp] = *(const bf8*)(fcW_bf + (size_t)(col0 + n) * 512 + k0 + kp);
        }
        __syncthreads();
        #pragma unroll
        for (int kk = 0; kk < 64; kk += 32) {
            bf8 a = *(const bf8*)&As[wid * 16 + m][kk + quad * 8];
            #pragma unroll
            for (int nt = 0; nt < 4; ++nt) {
                bf8 b = *(const bf8*)&Bs[nt * 16 + m][kk + quad * 8];
                acc[nt] = __builtin_amdgcn_mfma_f32_16x16x32_bf16(a, b, acc[nt], 0, 0, 0);
            }
        }
        __syncthreads();
    }
    #pragma unroll
    for (int nt = 0; nt < 4; ++nt) {
        #pragma unroll
        for (int r = 0; r < 4; ++r) {
            int col = col0 + nt * 16 + m;
            int rg  = row0 + wid * 16 + quad * 4 + r;
            float v = acc[nt][r] + fc_b[col];
            out[(size_t)rg * 1024 + col] = sigmoidf(v);
        }
    }
}

// ---------------------------------------------------------------- launcher
extern "C" void kernel_launch(void* const* d_in, const int* in_sizes, int n_in,
                              void* d_out, int out_size, void* d_ws, size_t ws_size,
                              hipStream_t stream)
{
    const float* msg      = (const float*)d_in[0];
    const float* embW     = (const float*)d_in[1];
    const float* emb_b    = (const float*)d_in[2];
    const float* init_emb = (const float*)d_in[3];
    const float* eln_g    = (const float*)d_in[4];
    const float* eln_b    = (const float*)d_in[5];
    const float* Wih      = (const float*)d_in[6];
    const float* Whh      = (const float*)d_in[7];
    const float* bih      = (const float*)d_in[8];
    const float* bhh      = (const float*)d_in[9];
    const float* gln_g    = (const float*)d_in[10];
    const float* gln_b    = (const float*)d_in[11];
    const float* fcW      = (const float*)d_in[12];
    const float* fc_b     = (const float*)d_in[13];
    float* out = (float*)d_out;

    // ws carve-out (shorts). Total 8,568,864 shorts = 17.1 MB.
    short* base    = (short*)d_ws;
    short* Whh_bf  = base;                        // 1536*512 = 786432
    short* Wih_bf  = Whh_bf + 1536 * 512;         // 1536*32  = 49152
    short* fcW_bf  = Wih_bf + 1536 * 32;          // 1024*512 = 524288
    short* embW_bf = fcW_bf + 1024 * 512;         // 32*8192  = 262144
    short* xs      = embW_bf + 32 * 8192;         // 5*4096*32 = 655360 (slot 0 unused)
    short* h0      = xs + 5 * 4096 * 32;          // 4096*512
    short* h1      = h0 + 4096 * 512;             // 4096*512
    short* hln     = h1 + 4096 * 512;             // 4096*512
    short* x0v     = hln + 4096 * 512;            // 32

    k_prep<<<512, 256, 0, stream>>>(Whh, Wih, fcW, embW, init_emb, eln_g, eln_b,
                                    Whh_bf, Wih_bf, fcW_bf, embW_bf, x0v, h0);
    k_embed<<<1024, 256, 0, stream>>>(msg, embW_bf, emb_b, eln_g, eln_b, xs);

    short* hi = h0;
    short* ho = h1;
    for (int t = 0; t < 5; ++t) {
        const short* xp = (t == 0) ? x0v : xs + (size_t)t * 4096 * 32;
        int xstride = (t == 0) ? 0 : 32;
        k_gru_step<<<dim3(64, 16), 256, 0, stream>>>(xp, xstride, hi, ho,
                                                     Whh_bf, Wih_bf, bih, bhh);
        short* tmp = hi; hi = ho; ho = tmp;
    }
    k_hln<<<1024, 256, 0, stream>>>(hi, gln_g, gln_b, hln);
    k_fc<<<dim3(64, 16), 256, 0, stream>>>(hln, fcW_bf, fc_b, out);
}